// Round 20
// baseline (177.892 us; speedup 1.0000x reference)
//
#include <hip/hip_runtime.h>

typedef unsigned int u32;
typedef unsigned short u16;
typedef __attribute__((ext_vector_type(8))) __bf16 bf16x8;
typedef __attribute__((ext_vector_type(4))) float f32x4;
typedef __attribute__((ext_vector_type(2))) unsigned int u32x2;

#define T_   16
#define HH   32
#define WW   32
#define HEADS_ 8
#define HD_  64
#define CC   512
#define NPOS 16384
#define QKS  1024   // QKV buffer holds Q|K only, stride 1024

__device__ __forceinline__ u16 f2bf(float f){
  u32 u = __builtin_bit_cast(u32, f);
  u32 r = u + 0x7FFFu + ((u >> 16) & 1u);
  return (u16)(r >> 16);
}

__device__ __forceinline__ u32 cvt_pk_bf16(float lo, float hi){
  u32 r;
  asm("v_cvt_pk_bf16_f32 %0, %1, %2" : "=v"(r) : "v"(lo), "v"(hi));
  return r;
}

__device__ __forceinline__ void gload16(const void* g, void* l){
  __builtin_amdgcn_global_load_lds(
    (const __attribute__((address_space(1))) void*)g,
    (__attribute__((address_space(3))) void*)l, 16, 0, 0);
}

// ---- weights: Wt[n][k] = w_*[k][n&511] (qkv concat), Wot[n][k] = w_o[k][n] --
__global__ __launch_bounds__(256) void k_convert_w(const float* __restrict__ wq,
                                                   const float* __restrict__ wk,
                                                   const float* __restrict__ wv,
                                                   const float* __restrict__ wo,
                                                   u16* __restrict__ wt,
                                                   u16* __restrict__ wot){
  int i = blockIdx.x * 256 + threadIdx.x;
  if (i < 1536*512){
    int n = i >> 9, k = i & 511;
    const float* src = (n < 512) ? wq : (n < 1024) ? wk : wv;
    wt[i] = f2bf(src[k*512 + (n & 511)]);
  } else {
    int j = i - 1536*512;
    int n = j >> 9, k = j & 511;
    wot[j] = f2bf(wo[k*512 + n]);
  }
}

// ---- bf16 MFMA GEMM, A[M,K] x Bt[N,K]^T -> C[M,N]. 128x128 tile, BK=32 ------
// XCD-aware block swizzle (r8-verified): nwg % 8 == 0 -> bijective.
// AF32/BF32: that operand is fp32 in global; staging converts to bf16 via
// reg-stage (2x float4 -> 8x f2bf -> ds_write_b128 at the IDENTICAL byte
// address gload16 would write: chunk c -> byte c*16). Layout/swizzle/barrier
// semantics unchanged; replaces the separate k_convert_x pass.
template<int OUTMODE, bool AF32, bool BF32>
__global__ __launch_bounds__(256) void k_gemm_bt(
    const void* __restrict__ Ap, const void* __restrict__ Btp,
    void* __restrict__ C, const float* __restrict__ bias,
    int M, int N, int K)
{
  __shared__ u16 lds[2][2][128*32];
  const int tid = threadIdx.x;
  const int lane = tid & 63;
  const int l15 = lane & 15, lhi = lane >> 4;
  const int wv = tid >> 6;
  const int gx = gridDim.x;
  const int nwg = gx * gridDim.y;
  int flat = blockIdx.y * gx + blockIdx.x;
  flat = (flat & 7) * (nwg >> 3) + (flat >> 3);      // XCD-contiguous chunks
  const int tm = (flat / gx) * 128, tn = (flat % gx) * 128;
  const int wm = (wv >> 1) * 64, wn = (wv & 1) * 64;
  const int nk = K >> 5;

  auto cvt_store = [&](const float* s, char* dst){
    const float4 fa = *(const float4*)s;
    const float4 fb = *(const float4*)(s + 4);
    union { u16 h[8]; uint4 q; } o;
    o.h[0]=f2bf(fa.x); o.h[1]=f2bf(fa.y); o.h[2]=f2bf(fa.z); o.h[3]=f2bf(fa.w);
    o.h[4]=f2bf(fb.x); o.h[5]=f2bf(fb.y); o.h[6]=f2bf(fb.z); o.h[7]=f2bf(fb.w);
    *(uint4*)dst = o.q;
  };

  auto stage = [&](int buf, int kb){
    #pragma unroll
    for (int half = 0; half < 2; ++half){
      int c = tid + half*256;
      int row = c >> 2;
      int g = (c & 3) ^ ((c >> 3) & 3);
      const size_t aoff = (size_t)(tm + row) * K + (kb << 5) + (g << 3);
      if constexpr (AF32){
        cvt_store((const float*)Ap + aoff,
                  (char*)(&lds[buf][0][0]) + (size_t)c * 16);
      } else {
        char* la = (char*)(&lds[buf][0][0]) + ((c >> 6) << 10);
        gload16((const u16*)Ap + aoff, la);
      }
      const size_t boff = (size_t)(tn + row) * K + (kb << 5) + (g << 3);
      if constexpr (BF32){
        cvt_store((const float*)Btp + boff,
                  (char*)(&lds[buf][1][0]) + (size_t)c * 16);
      } else {
        char* lb = (char*)(&lds[buf][1][0]) + ((c >> 6) << 10);
        gload16((const u16*)Btp + boff, lb);
      }
    }
  };

  stage(0, 0);
  f32x4 acc[4][4];
  const f32x4 z4 = {0.f, 0.f, 0.f, 0.f};
  #pragma unroll
  for (int i = 0; i < 4; ++i)
    #pragma unroll
    for (int j = 0; j < 4; ++j) acc[i][j] = z4;
  __syncthreads();

  int buf = 0;
  for (int kb = 0; kb < nk; ++kb){
    if (kb + 1 < nk) stage(buf ^ 1, kb + 1);
    const char* la = (const char*)(&lds[buf][0][0]);
    const char* lb = (const char*)(&lds[buf][1][0]);
    bf16x8 af[4], bfr[4];
    #pragma unroll
    for (int ai = 0; ai < 4; ++ai){
      int row = wm + ai*16 + l15;
      af[ai] = *(const bf16x8*)(la + row*64 + ((lhi ^ ((row >> 1) & 3)) << 4));
    }
    #pragma unroll
    for (int bj = 0; bj < 4; ++bj){
      int row = wn + bj*16 + l15;
      bfr[bj] = *(const bf16x8*)(lb + row*64 + ((lhi ^ ((row >> 1) & 3)) << 4));
    }
    #pragma unroll
    for (int ai = 0; ai < 4; ++ai)
      #pragma unroll
      for (int bj = 0; bj < 4; ++bj)
        acc[ai][bj] = __builtin_amdgcn_mfma_f32_16x16x32_bf16(af[ai], bfr[bj], acc[ai][bj], 0, 0, 0);
    __syncthreads();
    buf ^= 1;
  }

  #pragma unroll
  for (int ai = 0; ai < 4; ++ai)
    #pragma unroll
    for (int bj = 0; bj < 4; ++bj)
      #pragma unroll
      for (int r = 0; r < 4; ++r){
        int rr = tm + wm + ai*16 + (lhi << 2) + r;
        int cc = tn + wn + bj*16 + l15;
        float v = acc[ai][bj][r];
        if (OUTMODE == 0) ((u16*)C)[(size_t)rr * N + cc] = f2bf(v);
        else              ((float*)C)[(size_t)rr * N + cc] = v + bias[cc];
      }
}

// ---- neighborhood attention: LDS-staged, double-buffered --------------------
// VERBATIM round-15/19 passing kernel (93.4us). FROZEN: inner-loop source
// changes flip a latent codegen failure (r16/r17/r18); do not modify.
__global__ __launch_bounds__(512) void k_attn(const u16* __restrict__ qkv,
                                              const u16* __restrict__ vt,
                                              u16* __restrict__ ao){
  __shared__ u16 ldsK[2][16384];   // 2 x 32KB
  __shared__ u16 ldsV[2][16384];   // 2 x 32KB
  const int tid = threadIdx.x;
  const int lane = tid & 63;
  const int wv = tid >> 6;
  const int l15 = lane & 15, lhi = lane >> 4;
  const int bid = blockIdx.x;
  const int head = bid & 7;
  const int sp = bid >> 3;              // 0..127
  const int hrow = sp >> 2, wg = sp & 3;
  const int wq = (wg << 3) + wv;        // this wave's query w
  const int hw = (hrow << 5) + wq;      // query spatial index
  const int hs = min(max(hrow - 3, 0), HH - 7);
  const int cb = min(max((wg << 3) - 3, 0), 18);          // tile col base
  const int offw = min(max(wq - 3, 0), WW - 7) - cb;      // 0..7

  // Q as B-frag: col t = l15, k = d = lhi*8+j (and +32)   [r5-verified]
  const size_t qoff = ((size_t)hw * 16 + l15) * QKS + head * HD_ + (lhi << 3);
  const bf16x8 qb0 = *(const bf16x8*)(qkv + qoff);
  const bf16x8 qb1 = *(const bf16x8*)(qkv + qoff + 32);

  // t-window mask: col t = l15, rows t' = lhi*4+r          [r5-verified]
  const int tst = min(max(l15 - 3, 0), T_ - 7);
  bool val[4];
  #pragma unroll
  for (int r = 0; r < 4; ++r){
    int tp = (lhi << 2) + r;
    val[r] = (tp >= tst) && (tp < tst + 7);
  }

  const int srcb = l15 + ((lhi & 1) << 5);   // shfl source base   [r5]
  const bool bval = (lhi < 2);               // B-frag k<16 only   [r5]

  auto stageK = [&](int buf, int jh){
    const int hw0 = ((hs + jh) << 5) + cb;
    #pragma unroll
    for (int rnd = 0; rnd < 4; ++rnd){
      int c = tid + (rnd << 9);              // dest slot chunk 0..2047
      int lc = c ^ ((c >> 3) & 7);           // logical chunk (involution)
      int s = lc >> 7, tt = (lc >> 3) & 15, ch16 = lc & 7;
      const u16* src = qkv + ((size_t)(hw0 + s) * 16 + tt) * QKS + CC + head * HD_ + (ch16 << 3);
      gload16(src, &ldsK[buf][(size_t)((rnd << 9) + (wv << 6)) * 8]);
    }
  };
  auto stageV = [&](int buf, int jh){
    const int mb = (((hs + jh) << 5) + cb) << 4;   // tile m base
    #pragma unroll
    for (int rnd = 0; rnd < 4; ++rnd){
      int c = tid + (rnd << 9);
      int lc = c ^ ((c >> 5) & 7);
      int d = lc >> 5, m16 = lc & 31;
      const u16* src = vt + (((size_t)(head * HD_ + d)) << 14) + mb + (m16 << 3);
      gload16(src, &ldsV[buf][(size_t)((rnd << 9) + (wv << 6)) * 8]);
    }
  };

  float mrun = -3.0e38f, lp = 0.f;
  f32x4 oacc[4];
  const f32x4 z4 = {0.f,0.f,0.f,0.f};
  #pragma unroll
  for (int c = 0; c < 4; ++c) oacc[c] = z4;

  stageK(0, 0); stageV(0, 0);
  __syncthreads();

  int buf = 0;
  const int sw_ = (l15 & 7) << 4;            // read-side XOR swizzle
  for (int jh = 0; jh < 7; ++jh){
    if (jh < 6){ stageK(buf ^ 1, jh + 1); stageV(buf ^ 1, jh + 1); }
    const char* KB = (const char*)&ldsK[buf][0];
    const char* VB = (const char*)&ldsV[buf][0];

    // -- QK from LDS: A-frag row t'=l15, k=ch; 2 MFMA per offset [r5 math] --
    f32x4 st[7];
    #pragma unroll
    for (int s = 0; s < 7; ++s){
      const int ab = ((offw + s) << 11) + (l15 << 7) + (lhi << 4);
      const bf16x8 ka0 = *(const bf16x8*)(KB + ((ab)      ^ sw_));
      const bf16x8 ka1 = *(const bf16x8*)(KB + ((ab + 64) ^ sw_));
      f32x4 acc = z4;
      acc = __builtin_amdgcn_mfma_f32_16x16x32_bf16(ka0, qb0, acc, 0, 0, 0);
      acc = __builtin_amdgcn_mfma_f32_16x16x32_bf16(ka1, qb1, acc, 0, 0, 0);
      st[s] = acc;
    }
    // -- softmax (t = l15 frame)  [r5 verbatim] --
    float tmax = -3.0e38f;
    #pragma unroll
    for (int s = 0; s < 7; ++s)
      #pragma unroll
      for (int r = 0; r < 4; ++r){
        float sv = val[r] ? st[s][r] : -1.0e30f;
        st[s][r] = sv;
        tmax = fmaxf(tmax, sv);
      }
    tmax = fmaxf(tmax, __shfl_xor(tmax, 16));
    tmax = fmaxf(tmax, __shfl_xor(tmax, 32));
    const float mnew = fmaxf(mrun, tmax);
    const float sc = __expf(mrun - mnew);
    mrun = mnew;
    lp *= sc;
    #pragma unroll
    for (int c = 0; c < 4; ++c){
      oacc[c][0] *= sc; oacc[c][1] *= sc; oacc[c][2] *= sc; oacc[c][3] *= sc;
    }
    // -- P + PV (unpaired, zero-padded)  [r5 verbatim, va from LDS] --
    #pragma unroll
    for (int s = 0; s < 7; ++s){
      float p0 = __expf(st[s][0] - mnew);
      float p1 = __expf(st[s][1] - mnew);
      float p2 = __expf(st[s][2] - mnew);
      float p3 = __expf(st[s][3] - mnew);
      lp += (p0 + p1) + (p2 + p3);
      u32 px = cvt_pk_bf16(p0, p1);
      u32 py = cvt_pk_bf16(p2, p3);
      u32 w0 = __shfl(px, srcb);
      u32 w1 = __shfl(py, srcb);
      u32 w2 = __shfl(px, srcb + 16);
      u32 w3 = __shfl(py, srcb + 16);
      union { u32 u[4]; bf16x8 v; } bb;
      bb.u[0] = bval ? w0 : 0u;
      bb.u[1] = bval ? w1 : 0u;
      bb.u[2] = bval ? w2 : 0u;
      bb.u[3] = bval ? w3 : 0u;
      #pragma unroll
      for (int c = 0; c < 4; ++c){
        const int d = (c << 4) + l15;
        const int vb_ = (d << 9) + ((offw + s) << 5) + (lhi << 4);
        const bf16x8 va = *(const bf16x8*)(VB + (vb_ ^ sw_));
        oacc[c] = __builtin_amdgcn_mfma_f32_16x16x32_bf16(va, bb.v, oacc[c], 0, 0, 0);
      }
    }
    __syncthreads();
    buf ^= 1;
  }

  float lsum = lp;
  lsum += __shfl_xor(lsum, 16);
  lsum += __shfl_xor(lsum, 32);
  const float inv = 1.0f / lsum;             // lane-local: t = l15 frame

  const size_t obase = ((size_t)hw * 16 + l15) * CC + head * HD_ + (lhi << 2);
  #pragma unroll
  for (int c = 0; c < 4; ++c){
    u32x2 o;
    o.x = cvt_pk_bf16(oacc[c][0] * inv, oacc[c][1] * inv);
    o.y = cvt_pk_bf16(oacc[c][2] * inv, oacc[c][3] * inv);
    *(u32x2*)(ao + obase + c * 16) = o;      // d = c*16 + lhi*4 + 0..3
  }
}

// ---------------------------------------------------------------------------
extern "C" void kernel_launch(void* const* d_in, const int* in_sizes, int n_in,
                              void* d_out, int out_size, void* d_ws, size_t ws_size,
                              hipStream_t stream){
  const float* x  = (const float*)d_in[0];
  const float* wq = (const float*)d_in[1];
  const float* wk = (const float*)d_in[2];
  const float* wv = (const float*)d_in[3];
  const float* wo = (const float*)d_in[4];
  const float* bo = (const float*)d_in[5];

  char* ws = (char*)d_ws;
  u16* Wt  = (u16*)(ws);                    //  1,572,864 B
  u16* Wot = (u16*)(ws + 1572864);          //    524,288 B
  u16* QKV = (u16*)(ws + 2097152);          // 33,554,432 B (Q|K, stride 1024)
  u16* Vt  = (u16*)(ws + 35651584);         // 16,777,216 B
  u16* AO  = (u16*)(ws + 52428800);         // 16,777,216 B (total 69,206,016)

  k_convert_w<<<4096, 256, 0, stream>>>(wq, wk, wv, wo, Wt, Wot);
  // QK projection: A = x (fp32, converted in staging), Bt = Wt
  { dim3 g(8, 128);  k_gemm_bt<0, true, false><<<g, 256, 0, stream>>>(x, Wt, QKV, nullptr, 16384, 1024, 512); }
  // Vt = Wv^T * X^T : A = Wt rows [1024,1536), Bt = x (fp32, converted)
  { dim3 g(128, 4);  k_gemm_bt<0, false, true><<<g, 256, 0, stream>>>(Wt + 1024*512, x, Vt, nullptr, 512, 16384, 512); }
  k_attn<<<1024, 512, 0, stream>>>(QKV, Vt, AO);
  { dim3 g(4, 128);  k_gemm_bt<1, false, false><<<g, 256, 0, stream>>>(AO, Wot, (float*)d_out, bo, 16384, 512, 512); }
}

// Round 21
// 158.855 us; speedup vs baseline: 1.1198x; 1.1198x over previous
//
#include <hip/hip_runtime.h>

typedef unsigned int u32;
typedef unsigned short u16;
typedef __attribute__((ext_vector_type(8))) __bf16 bf16x8;
typedef __attribute__((ext_vector_type(4))) float f32x4;
typedef __attribute__((ext_vector_type(2))) unsigned int u32x2;

#define T_   16
#define HH   32
#define WW   32
#define HEADS_ 8
#define HD_  64
#define CC   512
#define NPOS 16384
#define QKS  1024   // QKV buffer holds Q|K only, stride 1024

__device__ __forceinline__ u16 f2bf(float f){
  u32 u = __builtin_bit_cast(u32, f);
  u32 r = u + 0x7FFFu + ((u >> 16) & 1u);
  return (u16)(r >> 16);
}

__device__ __forceinline__ u32 cvt_pk_bf16(float lo, float hi){
  u32 r;
  asm("v_cvt_pk_bf16_f32 %0, %1, %2" : "=v"(r) : "v"(lo), "v"(hi));
  return r;
}

__device__ __forceinline__ void gload16(const void* g, void* l){
  __builtin_amdgcn_global_load_lds(
    (const __attribute__((address_space(1))) void*)g,
    (__attribute__((address_space(3))) void*)l, 16, 0, 0);
}

// ---- convert x (fp32 -> bf16), 8 elems/thread -------------------------------
// (r20 showed fusing this into GEMM staging regresses: reg-staged conversion
// loses the async global_load_lds path; the standalone pass runs at HBM BW.)
__global__ __launch_bounds__(256) void k_convert_x(const float* __restrict__ x,
                                                   u16* __restrict__ xb){
  int i = blockIdx.x * 256 + threadIdx.x;
  const float4 a = ((const float4*)x)[i*2];
  const float4 b = ((const float4*)x)[i*2+1];
  union { u16 h[8]; uint4 q; } o;
  o.h[0]=f2bf(a.x); o.h[1]=f2bf(a.y); o.h[2]=f2bf(a.z); o.h[3]=f2bf(a.w);
  o.h[4]=f2bf(b.x); o.h[5]=f2bf(b.y); o.h[6]=f2bf(b.z); o.h[7]=f2bf(b.w);
  ((uint4*)xb)[i] = o.q;
}

// ---- weights: Wt[n][k] = w_*[k][n&511] (qkv concat), Wot[n][k] = w_o[k][n] --
__global__ __launch_bounds__(256) void k_convert_w(const float* __restrict__ wq,
                                                   const float* __restrict__ wk,
                                                   const float* __restrict__ wv,
                                                   const float* __restrict__ wo,
                                                   u16* __restrict__ wt,
                                                   u16* __restrict__ wot){
  int i = blockIdx.x * 256 + threadIdx.x;
  if (i < 1536*512){
    int n = i >> 9, k = i & 511;
    const float* src = (n < 512) ? wq : (n < 1024) ? wk : wv;
    wt[i] = f2bf(src[k*512 + (n & 511)]);
  } else {
    int j = i - 1536*512;
    int n = j >> 9, k = j & 511;
    wot[j] = f2bf(wo[k*512 + n]);
  }
}

// ---- bf16 MFMA GEMM, A[M,K] x Bt[N,K]^T -> C[M,N]. 128x128 tile, BK=32 ------
// XCD-aware block swizzle (r8-verified): nwg % 8 == 0 -> bijective.
template<int OUTMODE>
__global__ __launch_bounds__(256) void k_gemm_bt(
    const u16* __restrict__ A, const u16* __restrict__ Bt,
    void* __restrict__ C, const float* __restrict__ bias,
    int M, int N, int K)
{
  __shared__ u16 lds[2][2][128*32];
  const int tid = threadIdx.x;
  const int lane = tid & 63;
  const int l15 = lane & 15, lhi = lane >> 4;
  const int wv = tid >> 6;
  const int gx = gridDim.x;
  const int nwg = gx * gridDim.y;
  int flat = blockIdx.y * gx + blockIdx.x;
  flat = (flat & 7) * (nwg >> 3) + (flat >> 3);      // XCD-contiguous chunks
  const int tm = (flat / gx) * 128, tn = (flat % gx) * 128;
  const int wm = (wv >> 1) * 64, wn = (wv & 1) * 64;
  const int nk = K >> 5;

  auto stage = [&](int buf, int kb){
    #pragma unroll
    for (int half = 0; half < 2; ++half){
      int c = tid + half*256;
      int row = c >> 2;
      int g = (c & 3) ^ ((c >> 3) & 3);
      char* la = (char*)(&lds[buf][0][0]) + ((c >> 6) << 10);
      gload16(A + (size_t)(tm + row) * K + (kb << 5) + (g << 3), la);
      char* lb = (char*)(&lds[buf][1][0]) + ((c >> 6) << 10);
      gload16(Bt + (size_t)(tn + row) * K + (kb << 5) + (g << 3), lb);
    }
  };

  stage(0, 0);
  f32x4 acc[4][4];
  const f32x4 z4 = {0.f, 0.f, 0.f, 0.f};
  #pragma unroll
  for (int i = 0; i < 4; ++i)
    #pragma unroll
    for (int j = 0; j < 4; ++j) acc[i][j] = z4;
  __syncthreads();

  int buf = 0;
  for (int kb = 0; kb < nk; ++kb){
    if (kb + 1 < nk) stage(buf ^ 1, kb + 1);
    const char* la = (const char*)(&lds[buf][0][0]);
    const char* lb = (const char*)(&lds[buf][1][0]);
    bf16x8 af[4], bfr[4];
    #pragma unroll
    for (int ai = 0; ai < 4; ++ai){
      int row = wm + ai*16 + l15;
      af[ai] = *(const bf16x8*)(la + row*64 + ((lhi ^ ((row >> 1) & 3)) << 4));
    }
    #pragma unroll
    for (int bj = 0; bj < 4; ++bj){
      int row = wn + bj*16 + l15;
      bfr[bj] = *(const bf16x8*)(lb + row*64 + ((lhi ^ ((row >> 1) & 3)) << 4));
    }
    #pragma unroll
    for (int ai = 0; ai < 4; ++ai)
      #pragma unroll
      for (int bj = 0; bj < 4; ++bj)
        acc[ai][bj] = __builtin_amdgcn_mfma_f32_16x16x32_bf16(af[ai], bfr[bj], acc[ai][bj], 0, 0, 0);
    __syncthreads();
    buf ^= 1;
  }

  #pragma unroll
  for (int ai = 0; ai < 4; ++ai)
    #pragma unroll
    for (int bj = 0; bj < 4; ++bj)
      #pragma unroll
      for (int r = 0; r < 4; ++r){
        int rr = tm + wm + ai*16 + (lhi << 2) + r;
        int cc = tn + wn + bj*16 + l15;
        float v = acc[ai][bj][r];
        if (OUTMODE == 0) ((u16*)C)[(size_t)rr * N + cc] = f2bf(v);
        else              ((float*)C)[(size_t)rr * N + cc] = v + bias[cc];
      }
}

// ---- neighborhood attention: LDS-staged, double-buffered --------------------
// VERBATIM round-15/19 passing kernel (93.4us). FROZEN: inner-loop source
// changes flip a latent codegen failure (r16/r17/r18); do not modify.
__global__ __launch_bounds__(512) void k_attn(const u16* __restrict__ qkv,
                                              const u16* __restrict__ vt,
                                              u16* __restrict__ ao){
  __shared__ u16 ldsK[2][16384];   // 2 x 32KB
  __shared__ u16 ldsV[2][16384];   // 2 x 32KB
  const int tid = threadIdx.x;
  const int lane = tid & 63;
  const int wv = tid >> 6;
  const int l15 = lane & 15, lhi = lane >> 4;
  const int bid = blockIdx.x;
  const int head = bid & 7;
  const int sp = bid >> 3;              // 0..127
  const int hrow = sp >> 2, wg = sp & 3;
  const int wq = (wg << 3) + wv;        // this wave's query w
  const int hw = (hrow << 5) + wq;      // query spatial index
  const int hs = min(max(hrow - 3, 0), HH - 7);
  const int cb = min(max((wg << 3) - 3, 0), 18);          // tile col base
  const int offw = min(max(wq - 3, 0), WW - 7) - cb;      // 0..7

  // Q as B-frag: col t = l15, k = d = lhi*8+j (and +32)   [r5-verified]
  const size_t qoff = ((size_t)hw * 16 + l15) * QKS + head * HD_ + (lhi << 3);
  const bf16x8 qb0 = *(const bf16x8*)(qkv + qoff);
  const bf16x8 qb1 = *(const bf16x8*)(qkv + qoff + 32);

  // t-window mask: col t = l15, rows t' = lhi*4+r          [r5-verified]
  const int tst = min(max(l15 - 3, 0), T_ - 7);
  bool val[4];
  #pragma unroll
  for (int r = 0; r < 4; ++r){
    int tp = (lhi << 2) + r;
    val[r] = (tp >= tst) && (tp < tst + 7);
  }

  const int srcb = l15 + ((lhi & 1) << 5);   // shfl source base   [r5]
  const bool bval = (lhi < 2);               // B-frag k<16 only   [r5]

  auto stageK = [&](int buf, int jh){
    const int hw0 = ((hs + jh) << 5) + cb;
    #pragma unroll
    for (int rnd = 0; rnd < 4; ++rnd){
      int c = tid + (rnd << 9);              // dest slot chunk 0..2047
      int lc = c ^ ((c >> 3) & 7);           // logical chunk (involution)
      int s = lc >> 7, tt = (lc >> 3) & 15, ch16 = lc & 7;
      const u16* src = qkv + ((size_t)(hw0 + s) * 16 + tt) * QKS + CC + head * HD_ + (ch16 << 3);
      gload16(src, &ldsK[buf][(size_t)((rnd << 9) + (wv << 6)) * 8]);
    }
  };
  auto stageV = [&](int buf, int jh){
    const int mb = (((hs + jh) << 5) + cb) << 4;   // tile m base
    #pragma unroll
    for (int rnd = 0; rnd < 4; ++rnd){
      int c = tid + (rnd << 9);
      int lc = c ^ ((c >> 5) & 7);
      int d = lc >> 5, m16 = lc & 31;
      const u16* src = vt + (((size_t)(head * HD_ + d)) << 14) + mb + (m16 << 3);
      gload16(src, &ldsV[buf][(size_t)((rnd << 9) + (wv << 6)) * 8]);
    }
  };

  float mrun = -3.0e38f, lp = 0.f;
  f32x4 oacc[4];
  const f32x4 z4 = {0.f,0.f,0.f,0.f};
  #pragma unroll
  for (int c = 0; c < 4; ++c) oacc[c] = z4;

  stageK(0, 0); stageV(0, 0);
  __syncthreads();

  int buf = 0;
  const int sw_ = (l15 & 7) << 4;            // read-side XOR swizzle
  for (int jh = 0; jh < 7; ++jh){
    if (jh < 6){ stageK(buf ^ 1, jh + 1); stageV(buf ^ 1, jh + 1); }
    const char* KB = (const char*)&ldsK[buf][0];
    const char* VB = (const char*)&ldsV[buf][0];

    // -- QK from LDS: A-frag row t'=l15, k=ch; 2 MFMA per offset [r5 math] --
    f32x4 st[7];
    #pragma unroll
    for (int s = 0; s < 7; ++s){
      const int ab = ((offw + s) << 11) + (l15 << 7) + (lhi << 4);
      const bf16x8 ka0 = *(const bf16x8*)(KB + ((ab)      ^ sw_));
      const bf16x8 ka1 = *(const bf16x8*)(KB + ((ab + 64) ^ sw_));
      f32x4 acc = z4;
      acc = __builtin_amdgcn_mfma_f32_16x16x32_bf16(ka0, qb0, acc, 0, 0, 0);
      acc = __builtin_amdgcn_mfma_f32_16x16x32_bf16(ka1, qb1, acc, 0, 0, 0);
      st[s] = acc;
    }
    // -- softmax (t = l15 frame)  [r5 verbatim] --
    float tmax = -3.0e38f;
    #pragma unroll
    for (int s = 0; s < 7; ++s)
      #pragma unroll
      for (int r = 0; r < 4; ++r){
        float sv = val[r] ? st[s][r] : -1.0e30f;
        st[s][r] = sv;
        tmax = fmaxf(tmax, sv);
      }
    tmax = fmaxf(tmax, __shfl_xor(tmax, 16));
    tmax = fmaxf(tmax, __shfl_xor(tmax, 32));
    const float mnew = fmaxf(mrun, tmax);
    const float sc = __expf(mrun - mnew);
    mrun = mnew;
    lp *= sc;
    #pragma unroll
    for (int c = 0; c < 4; ++c){
      oacc[c][0] *= sc; oacc[c][1] *= sc; oacc[c][2] *= sc; oacc[c][3] *= sc;
    }
    // -- P + PV (unpaired, zero-padded)  [r5 verbatim, va from LDS] --
    #pragma unroll
    for (int s = 0; s < 7; ++s){
      float p0 = __expf(st[s][0] - mnew);
      float p1 = __expf(st[s][1] - mnew);
      float p2 = __expf(st[s][2] - mnew);
      float p3 = __expf(st[s][3] - mnew);
      lp += (p0 + p1) + (p2 + p3);
      u32 px = cvt_pk_bf16(p0, p1);
      u32 py = cvt_pk_bf16(p2, p3);
      u32 w0 = __shfl(px, srcb);
      u32 w1 = __shfl(py, srcb);
      u32 w2 = __shfl(px, srcb + 16);
      u32 w3 = __shfl(py, srcb + 16);
      union { u32 u[4]; bf16x8 v; } bb;
      bb.u[0] = bval ? w0 : 0u;
      bb.u[1] = bval ? w1 : 0u;
      bb.u[2] = bval ? w2 : 0u;
      bb.u[3] = bval ? w3 : 0u;
      #pragma unroll
      for (int c = 0; c < 4; ++c){
        const int d = (c << 4) + l15;
        const int vb_ = (d << 9) + ((offw + s) << 5) + (lhi << 4);
        const bf16x8 va = *(const bf16x8*)(VB + (vb_ ^ sw_));
        oacc[c] = __builtin_amdgcn_mfma_f32_16x16x32_bf16(va, bb.v, oacc[c], 0, 0, 0);
      }
    }
    __syncthreads();
    buf ^= 1;
  }

  float lsum = lp;
  lsum += __shfl_xor(lsum, 16);
  lsum += __shfl_xor(lsum, 32);
  const float inv = 1.0f / lsum;             // lane-local: t = l15 frame

  const size_t obase = ((size_t)hw * 16 + l15) * CC + head * HD_ + (lhi << 2);
  #pragma unroll
  for (int c = 0; c < 4; ++c){
    u32x2 o;
    o.x = cvt_pk_bf16(oacc[c][0] * inv, oacc[c][1] * inv);
    o.y = cvt_pk_bf16(oacc[c][2] * inv, oacc[c][3] * inv);
    *(u32x2*)(ao + obase + c * 16) = o;      // d = c*16 + lhi*4 + 0..3
  }
}

// ---------------------------------------------------------------------------
extern "C" void kernel_launch(void* const* d_in, const int* in_sizes, int n_in,
                              void* d_out, int out_size, void* d_ws, size_t ws_size,
                              hipStream_t stream){
  const float* x  = (const float*)d_in[0];
  const float* wq = (const float*)d_in[1];
  const float* wk = (const float*)d_in[2];
  const float* wv = (const float*)d_in[3];
  const float* wo = (const float*)d_in[4];
  const float* bo = (const float*)d_in[5];

  char* ws = (char*)d_ws;
  u16* Xb  = (u16*)(ws);                    // 16,777,216 B
  u16* Wt  = (u16*)(ws + 16777216);         //  1,572,864 B
  u16* Wot = (u16*)(ws + 18350080);         //    524,288 B
  u16* QKV = (u16*)(ws + 18874368);         // 33,554,432 B (Q|K, stride 1024)
  u16* Vt  = (u16*)(ws + 52428800);         // 16,777,216 B
  u16* AO  = (u16*)(ws + 69206016);         // 16,777,216 B (total 85,983,232)

  k_convert_x<<<4096, 256, 0, stream>>>(x, Xb);
  k_convert_w<<<4096, 256, 0, stream>>>(wq, wk, wv, wo, Wt, Wot);
  // QK projection: [16384,512] x [512,1024] -> QKV (stride 1024)
  { dim3 g(8, 128);  k_gemm_bt<0><<<g, 256, 0, stream>>>(Xb, Wt, QKV, nullptr, 16384, 1024, 512); }
  // Vt = Wv^T * X^T : A = Wt rows [1024,1536), Bt = Xb -> C[ch][m] = Vt
  { dim3 g(128, 4);  k_gemm_bt<0><<<g, 256, 0, stream>>>(Wt + 1024*512, Xb, Vt, nullptr, 512, 16384, 512); }
  k_attn<<<1024, 512, 0, stream>>>(QKV, Vt, AO);
  { dim3 g(4, 128);  k_gemm_bt<1><<<g, 256, 0, stream>>>(AO, Wot, (float*)d_out, bo, 16384, 512, 512); }
}

// Round 22
// 158.469 us; speedup vs baseline: 1.1226x; 1.0024x over previous
//
#include <hip/hip_runtime.h>

typedef unsigned int u32;
typedef unsigned short u16;
typedef __attribute__((ext_vector_type(8))) __bf16 bf16x8;
typedef __attribute__((ext_vector_type(4))) float f32x4;
typedef __attribute__((ext_vector_type(2))) unsigned int u32x2;

#define T_   16
#define HH   32
#define WW   32
#define HEADS_ 8
#define HD_  64
#define CC   512
#define NPOS 16384
#define QKS  1024   // QKV buffer holds Q|K only, stride 1024

__device__ __forceinline__ u16 f2bf(float f){
  u32 u = __builtin_bit_cast(u32, f);
  u32 r = u + 0x7FFFu + ((u >> 16) & 1u);
  return (u16)(r >> 16);
}

__device__ __forceinline__ u32 cvt_pk_bf16(float lo, float hi){
  u32 r;
  asm("v_cvt_pk_bf16_f32 %0, %1, %2" : "=v"(r) : "v"(lo), "v"(hi));
  return r;
}

__device__ __forceinline__ void gload16(const void* g, void* l){
  __builtin_amdgcn_global_load_lds(
    (const __attribute__((address_space(1))) void*)g,
    (__attribute__((address_space(3))) void*)l, 16, 0, 0);
}

// ---- convert x (fp32 -> bf16), 8 elems/thread -------------------------------
// (r20 showed fusing this into GEMM staging regresses: reg-staged conversion
// loses the async global_load_lds path; the standalone pass runs at HBM BW.)
__global__ __launch_bounds__(256) void k_convert_x(const float* __restrict__ x,
                                                   u16* __restrict__ xb){
  int i = blockIdx.x * 256 + threadIdx.x;
  const float4 a = ((const float4*)x)[i*2];
  const float4 b = ((const float4*)x)[i*2+1];
  union { u16 h[8]; uint4 q; } o;
  o.h[0]=f2bf(a.x); o.h[1]=f2bf(a.y); o.h[2]=f2bf(a.z); o.h[3]=f2bf(a.w);
  o.h[4]=f2bf(b.x); o.h[5]=f2bf(b.y); o.h[6]=f2bf(b.z); o.h[7]=f2bf(b.w);
  ((uint4*)xb)[i] = o.q;
}

// ---- weights: Wt[n][k] = w_*[k][n&511] (qkv concat), Wot[n][k] = w_o[k][n] --
__global__ __launch_bounds__(256) void k_convert_w(const float* __restrict__ wq,
                                                   const float* __restrict__ wk,
                                                   const float* __restrict__ wv,
                                                   const float* __restrict__ wo,
                                                   u16* __restrict__ wt,
                                                   u16* __restrict__ wot){
  int i = blockIdx.x * 256 + threadIdx.x;
  if (i < 1536*512){
    int n = i >> 9, k = i & 511;
    const float* src = (n < 512) ? wq : (n < 1024) ? wk : wv;
    wt[i] = f2bf(src[k*512 + (n & 511)]);
  } else {
    int j = i - 1536*512;
    int n = j >> 9, k = j & 511;
    wot[j] = f2bf(wo[k*512 + n]);
  }
}

// ---- bf16 MFMA GEMM, A[M,K] x Bt[N,K]^T -> C[M,N]. 128x128 tile, BK=32 ------
// XCD-aware block swizzle (r8-verified): nwg % 8 == 0 -> bijective.
template<int OUTMODE>
__global__ __launch_bounds__(256) void k_gemm_bt(
    const u16* __restrict__ A, const u16* __restrict__ Bt,
    void* __restrict__ C, const float* __restrict__ bias,
    int M, int N, int K)
{
  __shared__ u16 lds[2][2][128*32];
  const int tid = threadIdx.x;
  const int lane = tid & 63;
  const int l15 = lane & 15, lhi = lane >> 4;
  const int wv = tid >> 6;
  const int gx = gridDim.x;
  const int nwg = gx * gridDim.y;
  int flat = blockIdx.y * gx + blockIdx.x;
  flat = (flat & 7) * (nwg >> 3) + (flat >> 3);      // XCD-contiguous chunks
  const int tm = (flat / gx) * 128, tn = (flat % gx) * 128;
  const int wm = (wv >> 1) * 64, wn = (wv & 1) * 64;
  const int nk = K >> 5;

  auto stage = [&](int buf, int kb){
    #pragma unroll
    for (int half = 0; half < 2; ++half){
      int c = tid + half*256;
      int row = c >> 2;
      int g = (c & 3) ^ ((c >> 3) & 3);
      char* la = (char*)(&lds[buf][0][0]) + ((c >> 6) << 10);
      gload16(A + (size_t)(tm + row) * K + (kb << 5) + (g << 3), la);
      char* lb = (char*)(&lds[buf][1][0]) + ((c >> 6) << 10);
      gload16(Bt + (size_t)(tn + row) * K + (kb << 5) + (g << 3), lb);
    }
  };

  stage(0, 0);
  f32x4 acc[4][4];
  const f32x4 z4 = {0.f, 0.f, 0.f, 0.f};
  #pragma unroll
  for (int i = 0; i < 4; ++i)
    #pragma unroll
    for (int j = 0; j < 4; ++j) acc[i][j] = z4;
  __syncthreads();

  int buf = 0;
  for (int kb = 0; kb < nk; ++kb){
    if (kb + 1 < nk) stage(buf ^ 1, kb + 1);
    const char* la = (const char*)(&lds[buf][0][0]);
    const char* lb = (const char*)(&lds[buf][1][0]);
    bf16x8 af[4], bfr[4];
    #pragma unroll
    for (int ai = 0; ai < 4; ++ai){
      int row = wm + ai*16 + l15;
      af[ai] = *(const bf16x8*)(la + row*64 + ((lhi ^ ((row >> 1) & 3)) << 4));
    }
    #pragma unroll
    for (int bj = 0; bj < 4; ++bj){
      int row = wn + bj*16 + l15;
      bfr[bj] = *(const bf16x8*)(lb + row*64 + ((lhi ^ ((row >> 1) & 3)) << 4));
    }
    #pragma unroll
    for (int ai = 0; ai < 4; ++ai)
      #pragma unroll
      for (int bj = 0; bj < 4; ++bj)
        acc[ai][bj] = __builtin_amdgcn_mfma_f32_16x16x32_bf16(af[ai], bfr[bj], acc[ai][bj], 0, 0, 0);
    __syncthreads();
    buf ^= 1;
  }

  #pragma unroll
  for (int ai = 0; ai < 4; ++ai)
    #pragma unroll
    for (int bj = 0; bj < 4; ++bj)
      #pragma unroll
      for (int r = 0; r < 4; ++r){
        int rr = tm + wm + ai*16 + (lhi << 2) + r;
        int cc = tn + wn + bj*16 + l15;
        float v = acc[ai][bj][r];
        if (OUTMODE == 0) ((u16*)C)[(size_t)rr * N + cc] = f2bf(v);
        else              ((float*)C)[(size_t)rr * N + cc] = v + bias[cc];
      }
}

// ---- neighborhood attention: LDS-staged, double-buffered --------------------
// VERBATIM round-15/19 passing kernel (93.4us). FROZEN: inner-loop source
// changes flip a latent codegen failure (r16/r17/r18); do not modify.
__global__ __launch_bounds__(512) void k_attn(const u16* __restrict__ qkv,
                                              const u16* __restrict__ vt,
                                              u16* __restrict__ ao){
  __shared__ u16 ldsK[2][16384];   // 2 x 32KB
  __shared__ u16 ldsV[2][16384];   // 2 x 32KB
  const int tid = threadIdx.x;
  const int lane = tid & 63;
  const int wv = tid >> 6;
  const int l15 = lane & 15, lhi = lane >> 4;
  const int bid = blockIdx.x;
  const int head = bid & 7;
  const int sp = bid >> 3;              // 0..127
  const int hrow = sp >> 2, wg = sp & 3;
  const int wq = (wg << 3) + wv;        // this wave's query w
  const int hw = (hrow << 5) + wq;      // query spatial index
  const int hs = min(max(hrow - 3, 0), HH - 7);
  const int cb = min(max((wg << 3) - 3, 0), 18);          // tile col base
  const int offw = min(max(wq - 3, 0), WW - 7) - cb;      // 0..7

  // Q as B-frag: col t = l15, k = d = lhi*8+j (and +32)   [r5-verified]
  const size_t qoff = ((size_t)hw * 16 + l15) * QKS + head * HD_ + (lhi << 3);
  const bf16x8 qb0 = *(const bf16x8*)(qkv + qoff);
  const bf16x8 qb1 = *(const bf16x8*)(qkv + qoff + 32);

  // t-window mask: col t = l15, rows t' = lhi*4+r          [r5-verified]
  const int tst = min(max(l15 - 3, 0), T_ - 7);
  bool val[4];
  #pragma unroll
  for (int r = 0; r < 4; ++r){
    int tp = (lhi << 2) + r;
    val[r] = (tp >= tst) && (tp < tst + 7);
  }

  const int srcb = l15 + ((lhi & 1) << 5);   // shfl source base   [r5]
  const bool bval = (lhi < 2);               // B-frag k<16 only   [r5]

  auto stageK = [&](int buf, int jh){
    const int hw0 = ((hs + jh) << 5) + cb;
    #pragma unroll
    for (int rnd = 0; rnd < 4; ++rnd){
      int c = tid + (rnd << 9);              // dest slot chunk 0..2047
      int lc = c ^ ((c >> 3) & 7);           // logical chunk (involution)
      int s = lc >> 7, tt = (lc >> 3) & 15, ch16 = lc & 7;
      const u16* src = qkv + ((size_t)(hw0 + s) * 16 + tt) * QKS + CC + head * HD_ + (ch16 << 3);
      gload16(src, &ldsK[buf][(size_t)((rnd << 9) + (wv << 6)) * 8]);
    }
  };
  auto stageV = [&](int buf, int jh){
    const int mb = (((hs + jh) << 5) + cb) << 4;   // tile m base
    #pragma unroll
    for (int rnd = 0; rnd < 4; ++rnd){
      int c = tid + (rnd << 9);
      int lc = c ^ ((c >> 5) & 7);
      int d = lc >> 5, m16 = lc & 31;
      const u16* src = vt + (((size_t)(head * HD_ + d)) << 14) + mb + (m16 << 3);
      gload16(src, &ldsV[buf][(size_t)((rnd << 9) + (wv << 6)) * 8]);
    }
  };

  float mrun = -3.0e38f, lp = 0.f;
  f32x4 oacc[4];
  const f32x4 z4 = {0.f,0.f,0.f,0.f};
  #pragma unroll
  for (int c = 0; c < 4; ++c) oacc[c] = z4;

  stageK(0, 0); stageV(0, 0);
  __syncthreads();

  int buf = 0;
  const int sw_ = (l15 & 7) << 4;            // read-side XOR swizzle
  for (int jh = 0; jh < 7; ++jh){
    if (jh < 6){ stageK(buf ^ 1, jh + 1); stageV(buf ^ 1, jh + 1); }
    const char* KB = (const char*)&ldsK[buf][0];
    const char* VB = (const char*)&ldsV[buf][0];

    // -- QK from LDS: A-frag row t'=l15, k=ch; 2 MFMA per offset [r5 math] --
    f32x4 st[7];
    #pragma unroll
    for (int s = 0; s < 7; ++s){
      const int ab = ((offw + s) << 11) + (l15 << 7) + (lhi << 4);
      const bf16x8 ka0 = *(const bf16x8*)(KB + ((ab)      ^ sw_));
      const bf16x8 ka1 = *(const bf16x8*)(KB + ((ab + 64) ^ sw_));
      f32x4 acc = z4;
      acc = __builtin_amdgcn_mfma_f32_16x16x32_bf16(ka0, qb0, acc, 0, 0, 0);
      acc = __builtin_amdgcn_mfma_f32_16x16x32_bf16(ka1, qb1, acc, 0, 0, 0);
      st[s] = acc;
    }
    // -- softmax (t = l15 frame)  [r5 verbatim] --
    float tmax = -3.0e38f;
    #pragma unroll
    for (int s = 0; s < 7; ++s)
      #pragma unroll
      for (int r = 0; r < 4; ++r){
        float sv = val[r] ? st[s][r] : -1.0e30f;
        st[s][r] = sv;
        tmax = fmaxf(tmax, sv);
      }
    tmax = fmaxf(tmax, __shfl_xor(tmax, 16));
    tmax = fmaxf(tmax, __shfl_xor(tmax, 32));
    const float mnew = fmaxf(mrun, tmax);
    const float sc = __expf(mrun - mnew);
    mrun = mnew;
    lp *= sc;
    #pragma unroll
    for (int c = 0; c < 4; ++c){
      oacc[c][0] *= sc; oacc[c][1] *= sc; oacc[c][2] *= sc; oacc[c][3] *= sc;
    }
    // -- P + PV (unpaired, zero-padded)  [r5 verbatim, va from LDS] --
    #pragma unroll
    for (int s = 0; s < 7; ++s){
      float p0 = __expf(st[s][0] - mnew);
      float p1 = __expf(st[s][1] - mnew);
      float p2 = __expf(st[s][2] - mnew);
      float p3 = __expf(st[s][3] - mnew);
      lp += (p0 + p1) + (p2 + p3);
      u32 px = cvt_pk_bf16(p0, p1);
      u32 py = cvt_pk_bf16(p2, p3);
      u32 w0 = __shfl(px, srcb);
      u32 w1 = __shfl(py, srcb);
      u32 w2 = __shfl(px, srcb + 16);
      u32 w3 = __shfl(py, srcb + 16);
      union { u32 u[4]; bf16x8 v; } bb;
      bb.u[0] = bval ? w0 : 0u;
      bb.u[1] = bval ? w1 : 0u;
      bb.u[2] = bval ? w2 : 0u;
      bb.u[3] = bval ? w3 : 0u;
      #pragma unroll
      for (int c = 0; c < 4; ++c){
        const int d = (c << 4) + l15;
        const int vb_ = (d << 9) + ((offw + s) << 5) + (lhi << 4);
        const bf16x8 va = *(const bf16x8*)(VB + (vb_ ^ sw_));
        oacc[c] = __builtin_amdgcn_mfma_f32_16x16x32_bf16(va, bb.v, oacc[c], 0, 0, 0);
      }
    }
    __syncthreads();
    buf ^= 1;
  }

  float lsum = lp;
  lsum += __shfl_xor(lsum, 16);
  lsum += __shfl_xor(lsum, 32);
  const float inv = 1.0f / lsum;             // lane-local: t = l15 frame

  const size_t obase = ((size_t)hw * 16 + l15) * CC + head * HD_ + (lhi << 2);
  #pragma unroll
  for (int c = 0; c < 4; ++c){
    u32x2 o;
    o.x = cvt_pk_bf16(oacc[c][0] * inv, oacc[c][1] * inv);
    o.y = cvt_pk_bf16(oacc[c][2] * inv, oacc[c][3] * inv);
    *(u32x2*)(ao + obase + c * 16) = o;      // d = c*16 + lhi*4 + 0..3
  }
}

// ---------------------------------------------------------------------------
extern "C" void kernel_launch(void* const* d_in, const int* in_sizes, int n_in,
                              void* d_out, int out_size, void* d_ws, size_t ws_size,
                              hipStream_t stream){
  const float* x  = (const float*)d_in[0];
  const float* wq = (const float*)d_in[1];
  const float* wk = (const float*)d_in[2];
  const float* wv = (const float*)d_in[3];
  const float* wo = (const float*)d_in[4];
  const float* bo = (const float*)d_in[5];

  char* ws = (char*)d_ws;
  u16* Xb  = (u16*)(ws);                    // 16,777,216 B
  u16* Wt  = (u16*)(ws + 16777216);         //  1,572,864 B
  u16* Wot = (u16*)(ws + 18350080);         //    524,288 B
  u16* QKV = (u16*)(ws + 18874368);         // 33,554,432 B (Q|K, stride 1024)
  u16* Vt  = (u16*)(ws + 52428800);         // 16,777,216 B
  u16* AO  = (u16*)(ws + 69206016);         // 16,777,216 B (total 85,983,232)

  k_convert_x<<<4096, 256, 0, stream>>>(x, Xb);
  k_convert_w<<<4096, 256, 0, stream>>>(wq, wk, wv, wo, Wt, Wot);
  // QK projection: [16384,512] x [512,1024] -> QKV (stride 1024)
  { dim3 g(8, 128);  k_gemm_bt<0><<<g, 256, 0, stream>>>(Xb, Wt, QKV, nullptr, 16384, 1024, 512); }
  // Vt = Wv^T * X^T : A = Wt rows [1024,1536), Bt = Xb -> C[ch][m] = Vt
  { dim3 g(128, 4);  k_gemm_bt<0><<<g, 256, 0, stream>>>(Wt + 1024*512, Xb, Vt, nullptr, 512, 16384, 512); }
  k_attn<<<1024, 512, 0, stream>>>(QKV, Vt, AO);
  { dim3 g(4, 128);  k_gemm_bt<1><<<g, 256, 0, stream>>>(AO, Wot, (float*)d_out, bo, 16384, 512, 512); }
}

// Round 23
// 149.630 us; speedup vs baseline: 1.1889x; 1.0591x over previous
//
#include <hip/hip_runtime.h>

typedef unsigned int u32;
typedef unsigned short u16;
typedef __attribute__((ext_vector_type(8))) __bf16 bf16x8;
typedef __attribute__((ext_vector_type(4))) float f32x4;
typedef __attribute__((ext_vector_type(2))) unsigned int u32x2;

#define T_   16
#define HH   32
#define WW   32
#define HEADS_ 8
#define HD_  64
#define CC   512
#define NPOS 16384
#define QKS  1024   // QKV buffer holds Q|K only, stride 1024

__device__ __forceinline__ u16 f2bf(float f){
  u32 u = __builtin_bit_cast(u32, f);
  u32 r = u + 0x7FFFu + ((u >> 16) & 1u);
  return (u16)(r >> 16);
}

__device__ __forceinline__ u32 cvt_pk_bf16(float lo, float hi){
  u32 r;
  asm("v_cvt_pk_bf16_f32 %0, %1, %2" : "=v"(r) : "v"(lo), "v"(hi));
  return r;
}

__device__ __forceinline__ void gload16(const void* g, void* l){
  __builtin_amdgcn_global_load_lds(
    (const __attribute__((address_space(1))) void*)g,
    (__attribute__((address_space(3))) void*)l, 16, 0, 0);
}

// ---- fused converts: blocks [0,4096) = x fp32->bf16; [4096,8192) = weights --
__global__ __launch_bounds__(256) void k_convert(const float* __restrict__ x,
                                                 const float* __restrict__ wq,
                                                 const float* __restrict__ wk,
                                                 const float* __restrict__ wv,
                                                 const float* __restrict__ wo,
                                                 u16* __restrict__ xb,
                                                 u16* __restrict__ wt,
                                                 u16* __restrict__ wot){
  if (blockIdx.x < 4096){
    int i = blockIdx.x * 256 + threadIdx.x;
    const float4 a = ((const float4*)x)[i*2];
    const float4 b = ((const float4*)x)[i*2+1];
    union { u16 h[8]; uint4 q; } o;
    o.h[0]=f2bf(a.x); o.h[1]=f2bf(a.y); o.h[2]=f2bf(a.z); o.h[3]=f2bf(a.w);
    o.h[4]=f2bf(b.x); o.h[5]=f2bf(b.y); o.h[6]=f2bf(b.z); o.h[7]=f2bf(b.w);
    ((uint4*)xb)[i] = o.q;
  } else {
    int i = (blockIdx.x - 4096) * 256 + threadIdx.x;
    if (i < 1536*512){
      int n = i >> 9, k = i & 511;
      const float* src = (n < 512) ? wq : (n < 1024) ? wk : wv;
      wt[i] = f2bf(src[k*512 + (n & 511)]);
    } else {
      int j = i - 1536*512;
      int n = j >> 9, k = j & 511;
      wot[j] = f2bf(wo[k*512 + n]);
    }
  }
}

// ---- bf16 MFMA GEMM body (byte-identical math to the session-verified
// k_gemm_bt), parameterized on (flat0, gx, nwg) so multiple logical GEMMs can
// share one dispatch. XCD swizzle (r8-verified): nwg % 8 == 0 -> bijective.
template<int OUTMODE>
__device__ __forceinline__ void gemm_body(
    u16* ldsp,                      // 2*2*4096 u16 = 32KB
    const u16* __restrict__ A, const u16* __restrict__ Bt,
    void* __restrict__ C, const float* __restrict__ bias,
    int M, int N, int K, int flat0, int gx, int nwg)
{
  const int tid = threadIdx.x;
  const int lane = tid & 63;
  const int l15 = lane & 15, lhi = lane >> 4;
  const int wv = tid >> 6;
  int flat = (flat0 & 7) * (nwg >> 3) + (flat0 >> 3);   // XCD-contiguous chunks
  const int tm = (flat / gx) * 128, tn = (flat % gx) * 128;
  const int wm = (wv >> 1) * 64, wn = (wv & 1) * 64;
  const int nk = K >> 5;

  auto stage = [&](int buf, int kb){
    #pragma unroll
    for (int half = 0; half < 2; ++half){
      int c = tid + half*256;
      int row = c >> 2;
      int g = (c & 3) ^ ((c >> 3) & 3);
      char* la = (char*)(ldsp + (size_t)buf * 8192) + ((c >> 6) << 10);
      gload16(A + (size_t)(tm + row) * K + (kb << 5) + (g << 3), la);
      char* lb = (char*)(ldsp + (size_t)buf * 8192 + 4096) + ((c >> 6) << 10);
      gload16(Bt + (size_t)(tn + row) * K + (kb << 5) + (g << 3), lb);
    }
  };

  stage(0, 0);
  f32x4 acc[4][4];
  const f32x4 z4 = {0.f, 0.f, 0.f, 0.f};
  #pragma unroll
  for (int i = 0; i < 4; ++i)
    #pragma unroll
    for (int j = 0; j < 4; ++j) acc[i][j] = z4;
  __syncthreads();

  int buf = 0;
  for (int kb = 0; kb < nk; ++kb){
    if (kb + 1 < nk) stage(buf ^ 1, kb + 1);
    const char* la = (const char*)(ldsp + (size_t)buf * 8192);
    const char* lb = (const char*)(ldsp + (size_t)buf * 8192 + 4096);
    bf16x8 af[4], bfr[4];
    #pragma unroll
    for (int ai = 0; ai < 4; ++ai){
      int row = wm + ai*16 + l15;
      af[ai] = *(const bf16x8*)(la + row*64 + ((lhi ^ ((row >> 1) & 3)) << 4));
    }
    #pragma unroll
    for (int bj = 0; bj < 4; ++bj){
      int row = wn + bj*16 + l15;
      bfr[bj] = *(const bf16x8*)(lb + row*64 + ((lhi ^ ((row >> 1) & 3)) << 4));
    }
    #pragma unroll
    for (int ai = 0; ai < 4; ++ai)
      #pragma unroll
      for (int bj = 0; bj < 4; ++bj)
        acc[ai][bj] = __builtin_amdgcn_mfma_f32_16x16x32_bf16(af[ai], bfr[bj], acc[ai][bj], 0, 0, 0);
    __syncthreads();
    buf ^= 1;
  }

  #pragma unroll
  for (int ai = 0; ai < 4; ++ai)
    #pragma unroll
    for (int bj = 0; bj < 4; ++bj)
      #pragma unroll
      for (int r = 0; r < 4; ++r){
        int rr = tm + wm + ai*16 + (lhi << 2) + r;
        int cc = tn + wn + bj*16 + l15;
        float v = acc[ai][bj][r];
        if (OUTMODE == 0) ((u16*)C)[(size_t)rr * N + cc] = f2bf(v);
        else              ((float*)C)[(size_t)rr * N + cc] = v + bias[cc];
      }
}

// ---- merged middle GEMMs: blocks [0,1024) = QK proj; [1024,1536) = Vt ------
// The two GEMMs are independent (both read Xb/Wt) and the Vt GEMM alone
// under-fills the GPU (512 blocks = 2/CU); one dispatch lets them co-run.
__global__ __launch_bounds__(256) void k_gemm_dual(const u16* __restrict__ Xb,
                                                   const u16* __restrict__ Wt,
                                                   u16* __restrict__ QKV,
                                                   u16* __restrict__ Vt){
  __shared__ u16 lds[2][2][128*32];
  const int b = blockIdx.x;
  if (b < 1024){
    gemm_body<0>(&lds[0][0][0], Xb, Wt, QKV, nullptr,
                 16384, 1024, 512, b, 8, 1024);
  } else {
    gemm_body<0>(&lds[0][0][0], Wt + 1024*512, Xb, Vt, nullptr,
                 512, 16384, 512, b - 1024, 128, 512);
  }
}

// ---- output GEMM (thin wrapper over the same body) --------------------------
template<int OUTMODE>
__global__ __launch_bounds__(256) void k_gemm_bt(
    const u16* __restrict__ A, const u16* __restrict__ Bt,
    void* __restrict__ C, const float* __restrict__ bias,
    int M, int N, int K)
{
  __shared__ u16 lds[2][2][128*32];
  const int gx = gridDim.x;
  const int nwg = gx * gridDim.y;
  const int flat0 = blockIdx.y * gx + blockIdx.x;
  gemm_body<OUTMODE>(&lds[0][0][0], A, Bt, C, bias, M, N, K, flat0, gx, nwg);
}

// ---- neighborhood attention: LDS-staged, double-buffered --------------------
// VERBATIM round-15/19/22 passing kernel (93.4us). FROZEN: inner-loop source
// changes flip a latent codegen failure (r16/r17/r18); do not modify.
__global__ __launch_bounds__(512) void k_attn(const u16* __restrict__ qkv,
                                              const u16* __restrict__ vt,
                                              u16* __restrict__ ao){
  __shared__ u16 ldsK[2][16384];   // 2 x 32KB
  __shared__ u16 ldsV[2][16384];   // 2 x 32KB
  const int tid = threadIdx.x;
  const int lane = tid & 63;
  const int wv = tid >> 6;
  const int l15 = lane & 15, lhi = lane >> 4;
  const int bid = blockIdx.x;
  const int head = bid & 7;
  const int sp = bid >> 3;              // 0..127
  const int hrow = sp >> 2, wg = sp & 3;
  const int wq = (wg << 3) + wv;        // this wave's query w
  const int hw = (hrow << 5) + wq;      // query spatial index
  const int hs = min(max(hrow - 3, 0), HH - 7);
  const int cb = min(max((wg << 3) - 3, 0), 18);          // tile col base
  const int offw = min(max(wq - 3, 0), WW - 7) - cb;      // 0..7

  // Q as B-frag: col t = l15, k = d = lhi*8+j (and +32)   [r5-verified]
  const size_t qoff = ((size_t)hw * 16 + l15) * QKS + head * HD_ + (lhi << 3);
  const bf16x8 qb0 = *(const bf16x8*)(qkv + qoff);
  const bf16x8 qb1 = *(const bf16x8*)(qkv + qoff + 32);

  // t-window mask: col t = l15, rows t' = lhi*4+r          [r5-verified]
  const int tst = min(max(l15 - 3, 0), T_ - 7);
  bool val[4];
  #pragma unroll
  for (int r = 0; r < 4; ++r){
    int tp = (lhi << 2) + r;
    val[r] = (tp >= tst) && (tp < tst + 7);
  }

  const int srcb = l15 + ((lhi & 1) << 5);   // shfl source base   [r5]
  const bool bval = (lhi < 2);               // B-frag k<16 only   [r5]

  auto stageK = [&](int buf, int jh){
    const int hw0 = ((hs + jh) << 5) + cb;
    #pragma unroll
    for (int rnd = 0; rnd < 4; ++rnd){
      int c = tid + (rnd << 9);              // dest slot chunk 0..2047
      int lc = c ^ ((c >> 3) & 7);           // logical chunk (involution)
      int s = lc >> 7, tt = (lc >> 3) & 15, ch16 = lc & 7;
      const u16* src = qkv + ((size_t)(hw0 + s) * 16 + tt) * QKS + CC + head * HD_ + (ch16 << 3);
      gload16(src, &ldsK[buf][(size_t)((rnd << 9) + (wv << 6)) * 8]);
    }
  };
  auto stageV = [&](int buf, int jh){
    const int mb = (((hs + jh) << 5) + cb) << 4;   // tile m base
    #pragma unroll
    for (int rnd = 0; rnd < 4; ++rnd){
      int c = tid + (rnd << 9);
      int lc = c ^ ((c >> 5) & 7);
      int d = lc >> 5, m16 = lc & 31;
      const u16* src = vt + (((size_t)(head * HD_ + d)) << 14) + mb + (m16 << 3);
      gload16(src, &ldsV[buf][(size_t)((rnd << 9) + (wv << 6)) * 8]);
    }
  };

  float mrun = -3.0e38f, lp = 0.f;
  f32x4 oacc[4];
  const f32x4 z4 = {0.f,0.f,0.f,0.f};
  #pragma unroll
  for (int c = 0; c < 4; ++c) oacc[c] = z4;

  stageK(0, 0); stageV(0, 0);
  __syncthreads();

  int buf = 0;
  const int sw_ = (l15 & 7) << 4;            // read-side XOR swizzle
  for (int jh = 0; jh < 7; ++jh){
    if (jh < 6){ stageK(buf ^ 1, jh + 1); stageV(buf ^ 1, jh + 1); }
    const char* KB = (const char*)&ldsK[buf][0];
    const char* VB = (const char*)&ldsV[buf][0];

    // -- QK from LDS: A-frag row t'=l15, k=ch; 2 MFMA per offset [r5 math] --
    f32x4 st[7];
    #pragma unroll
    for (int s = 0; s < 7; ++s){
      const int ab = ((offw + s) << 11) + (l15 << 7) + (lhi << 4);
      const bf16x8 ka0 = *(const bf16x8*)(KB + ((ab)      ^ sw_));
      const bf16x8 ka1 = *(const bf16x8*)(KB + ((ab + 64) ^ sw_));
      f32x4 acc = z4;
      acc = __builtin_amdgcn_mfma_f32_16x16x32_bf16(ka0, qb0, acc, 0, 0, 0);
      acc = __builtin_amdgcn_mfma_f32_16x16x32_bf16(ka1, qb1, acc, 0, 0, 0);
      st[s] = acc;
    }
    // -- softmax (t = l15 frame)  [r5 verbatim] --
    float tmax = -3.0e38f;
    #pragma unroll
    for (int s = 0; s < 7; ++s)
      #pragma unroll
      for (int r = 0; r < 4; ++r){
        float sv = val[r] ? st[s][r] : -1.0e30f;
        st[s][r] = sv;
        tmax = fmaxf(tmax, sv);
      }
    tmax = fmaxf(tmax, __shfl_xor(tmax, 16));
    tmax = fmaxf(tmax, __shfl_xor(tmax, 32));
    const float mnew = fmaxf(mrun, tmax);
    const float sc = __expf(mrun - mnew);
    mrun = mnew;
    lp *= sc;
    #pragma unroll
    for (int c = 0; c < 4; ++c){
      oacc[c][0] *= sc; oacc[c][1] *= sc; oacc[c][2] *= sc; oacc[c][3] *= sc;
    }
    // -- P + PV (unpaired, zero-padded)  [r5 verbatim, va from LDS] --
    #pragma unroll
    for (int s = 0; s < 7; ++s){
      float p0 = __expf(st[s][0] - mnew);
      float p1 = __expf(st[s][1] - mnew);
      float p2 = __expf(st[s][2] - mnew);
      float p3 = __expf(st[s][3] - mnew);
      lp += (p0 + p1) + (p2 + p3);
      u32 px = cvt_pk_bf16(p0, p1);
      u32 py = cvt_pk_bf16(p2, p3);
      u32 w0 = __shfl(px, srcb);
      u32 w1 = __shfl(py, srcb);
      u32 w2 = __shfl(px, srcb + 16);
      u32 w3 = __shfl(py, srcb + 16);
      union { u32 u[4]; bf16x8 v; } bb;
      bb.u[0] = bval ? w0 : 0u;
      bb.u[1] = bval ? w1 : 0u;
      bb.u[2] = bval ? w2 : 0u;
      bb.u[3] = bval ? w3 : 0u;
      #pragma unroll
      for (int c = 0; c < 4; ++c){
        const int d = (c << 4) + l15;
        const int vb_ = (d << 9) + ((offw + s) << 5) + (lhi << 4);
        const bf16x8 va = *(const bf16x8*)(VB + (vb_ ^ sw_));
        oacc[c] = __builtin_amdgcn_mfma_f32_16x16x32_bf16(va, bb.v, oacc[c], 0, 0, 0);
      }
    }
    __syncthreads();
    buf ^= 1;
  }

  float lsum = lp;
  lsum += __shfl_xor(lsum, 16);
  lsum += __shfl_xor(lsum, 32);
  const float inv = 1.0f / lsum;             // lane-local: t = l15 frame

  const size_t obase = ((size_t)hw * 16 + l15) * CC + head * HD_ + (lhi << 2);
  #pragma unroll
  for (int c = 0; c < 4; ++c){
    u32x2 o;
    o.x = cvt_pk_bf16(oacc[c][0] * inv, oacc[c][1] * inv);
    o.y = cvt_pk_bf16(oacc[c][2] * inv, oacc[c][3] * inv);
    *(u32x2*)(ao + obase + c * 16) = o;      // d = c*16 + lhi*4 + 0..3
  }
}

// ---------------------------------------------------------------------------
extern "C" void kernel_launch(void* const* d_in, const int* in_sizes, int n_in,
                              void* d_out, int out_size, void* d_ws, size_t ws_size,
                              hipStream_t stream){
  const float* x  = (const float*)d_in[0];
  const float* wq = (const float*)d_in[1];
  const float* wk = (const float*)d_in[2];
  const float* wv = (const float*)d_in[3];
  const float* wo = (const float*)d_in[4];
  const float* bo = (const float*)d_in[5];

  char* ws = (char*)d_ws;
  u16* Xb  = (u16*)(ws);                    // 16,777,216 B
  u16* Wt  = (u16*)(ws + 16777216);         //  1,572,864 B
  u16* Wot = (u16*)(ws + 18350080);         //    524,288 B
  u16* QKV = (u16*)(ws + 18874368);         // 33,554,432 B (Q|K, stride 1024)
  u16* Vt  = (u16*)(ws + 52428800);         // 16,777,216 B
  u16* AO  = (u16*)(ws + 69206016);         // 16,777,216 B (total 85,983,232)

  k_convert<<<8192, 256, 0, stream>>>(x, wq, wk, wv, wo, Xb, Wt, Wot);
  k_gemm_dual<<<1536, 256, 0, stream>>>(Xb, Wt, QKV, Vt);
  k_attn<<<1024, 512, 0, stream>>>(QKV, Vt, AO);
  { dim3 g(4, 128);  k_gemm_bt<1><<<g, 256, 0, stream>>>(AO, Wot, (float*)d_out, bo, 16384, 512, 512); }
}